// Round 7
// baseline (185.855 us; speedup 1.0000x reference)
//
#include <hip/hip_runtime.h>

// SNN 2->8->8->1, 16 steps, leak=0.8, thr=0.5.
// R18 = 4/4 LUT split: kill the bank conflicts by shrinking the gather's
// VALUE DOMAIN (256 -> 16 entries), not by placement.
//
// R17 measurement (5x amplified loop): P=8.7us preamble+launch, L=16.5us
// loop. Kernel counters (first sighting): VGPR=28 (NO spills, ever),
// FETCH/WRITE = pure io, SQ_LDS_BANK_CONFLICT = 3.53e7 cyc/dispatch
// = 60% of kernel cycles = ~18 extra cyc per DS read. The 256-entry
// data-dependent gather requests ~57 DISTINCT 32B entries per wave per
// step -> ~8 distinct words per bank -> conflicts are intrinsic; no
// stride/width/schedule fixes it (R11/R13/R15/R16 all null, explained).
//
// Fix: dv chain split at k=4. lutA[16] = exact fma-chain prefix k=0..3
// (16 entries: 64 lanes over 16 values -> mostly same-address broadcast;
// stride 12 -> <=2 distinct addrs/bank = free per m136). Chain
// CONTINUATION k=4..7 in VALU: 32 fma/step, weights pinned to SGPR via
// readfirstlane (v_fmac v,s,v = 1 sgpr operand, legal). luto read stays.
// LDS/step/CU 2700 -> ~960 cyc (hidden under VALU); VALU/step 58 -> ~100
// -> loop ~10.7us. Predicted: dur 25.2 -> 19-21us, conflicts <2e6,
// VALUBusy ~50-55%. If >=24us: theory falsified -> disasm round.
//
// Bit-exactness invariants (absmax 0.0 R1-R17, preserved):
//  - contract(off): a*b + c stays mul+add everywhere
//  - dv_j = fma chain ascending k=0..7: lutA prefix (k=0..3, bits of
//    bLo) then runtime fma continuation (k=4..7, bits of bHi) is the
//    IDENTICAL per-op sequence -> identical bits
//  - m2 updates independent across j -> descending-j order bitwise same;
//    mk2 = 2*mk2+s descending == |= s<<j ascending
//  - reset (m>=0.5 ? 0 : m) == m*(1-s) bitwise
//  - L1 exactly periodic; F = 1 + #{t: c < B_t}, B_t constexpr bit-search
//  - unified LSB convention: neuron k = bit k everywhere

// ---- compile-time breakpoint search (bit-exact f32, IEEE RN per op) ----
constexpr bool spikes_by(float c, int p) {
    float m = 0.f;
    for (int t = 0; t < p; ++t) {
        float a = 0.8f * m;
        m = a + c;
        if (m >= 0.5f) return true;
    }
    return false;
}
constexpr unsigned find_B(int p) {
    unsigned lo = 0x3D4CCCCDu;  // 0.05f: never spikes
    unsigned hi = 0x3F19999Au;  // 0.6f : spikes at step 1
    while (hi - lo > 1u) {
        unsigned mid = lo + (hi - lo) / 2u;
        if (spikes_by(__builtin_bit_cast(float, mid), p)) hi = mid;
        else lo = mid;
    }
    return hi;
}
constexpr float kB[17] = {
    0.f,
    __builtin_bit_cast(float, find_B(1)),  __builtin_bit_cast(float, find_B(2)),
    __builtin_bit_cast(float, find_B(3)),  __builtin_bit_cast(float, find_B(4)),
    __builtin_bit_cast(float, find_B(5)),  __builtin_bit_cast(float, find_B(6)),
    __builtin_bit_cast(float, find_B(7)),  __builtin_bit_cast(float, find_B(8)),
    __builtin_bit_cast(float, find_B(9)),  __builtin_bit_cast(float, find_B(10)),
    __builtin_bit_cast(float, find_B(11)), __builtin_bit_cast(float, find_B(12)),
    __builtin_bit_cast(float, find_B(13)), __builtin_bit_cast(float, find_B(14)),
    __builtin_bit_cast(float, find_B(15)), __builtin_bit_cast(float, find_B(16))
};
constexpr unsigned mk_train(int F) {
    unsigned tr = 0;
    if (F <= 16) for (int t = F; t <= 16; t += F) tr |= 1u << (t - 1);
    return tr;
}
constexpr unsigned kTv[18] = {
    0, mk_train(1), mk_train(2),  mk_train(3),  mk_train(4),  mk_train(5),
    mk_train(6),  mk_train(7),  mk_train(8),  mk_train(9),  mk_train(10),
    mk_train(11), mk_train(12), mk_train(13), mk_train(14), mk_train(15),
    mk_train(16), mk_train(17)
};

__device__ __forceinline__ unsigned long long tr8(unsigned long long x) {
    unsigned long long t;
    t = (x ^ (x >> 7))  & 0x00AA00AA00AA00AAull; x = x ^ t ^ (t << 7);
    t = (x ^ (x >> 14)) & 0x0000CCCC0000CCCCull; x = x ^ t ^ (t << 14);
    t = (x ^ (x >> 28)) & 0x00000000F0F0F0F0ull; x = x ^ t ^ (t << 28);
    return x;
}

__device__ __forceinline__ float sgpr_f(float v) {
    // force SGPR residency of a wave-uniform float
    return __builtin_bit_cast(float,
        __builtin_amdgcn_readfirstlane(__builtin_bit_cast(int, v)));
}

__global__ __launch_bounds__(256, 8) void snn_kernel(
    const float* __restrict__ x,
    const float* __restrict__ W_ih, const float* __restrict__ b_ih,
    const float* __restrict__ W_hh, const float* __restrict__ b_hh,
    const float* __restrict__ W_ho, const float* __restrict__ b_ho,
    float* __restrict__ out, int n)
{
#pragma clang fp contract(off)
    // 16-entry prefix LUT, stride 12 floats (48B): 16B-aligned, 4-word
    // windows at 12q mod 32 -> 8 positions x 2 entries -> <=2-way = free.
    __shared__ __align__(16) float lutA[16 * 12];    // 768 B
    __shared__ float luto[256];                      // 1 KB
    __shared__ unsigned Tv[18];

    const int p = threadIdx.x;

    {   // builds: exact fma chains, neuron k at bit k (LSB)
        float bits[8];
#pragma unroll
        for (int k = 0; k < 8; ++k) bits[k] = (float)((p >> k) & 1);
        if (p < 16) {  // lutA entry p: chain PREFIX k=0..3 (bits of p)
            float e[8];
#pragma unroll
            for (int j = 0; j < 8; ++j) {
                float acc = 0.f;
#pragma unroll
                for (int k = 0; k < 4; ++k)
                    acc = __fmaf_rn(bits[k], W_hh[8 * j + k], acc);
                e[j] = acc;
            }
            float4* dst = reinterpret_cast<float4*>(&lutA[p * 12]);
            dst[0] = make_float4(e[0], e[1], e[2], e[3]);
            dst[1] = make_float4(e[4], e[5], e[6], e[7]);
        }
        float acc = 0.f;   // luto: full 8-bit chain (unchanged)
#pragma unroll
        for (int k = 0; k < 8; ++k)
            acc = __fmaf_rn(bits[k], W_ho[k], acc);
        luto[p] = acc;
    }
    if (p < 18) Tv[p] = kTv[p];
    __syncthreads();

    const int i = blockIdx.x * 256 + p;
    if (i >= n) return;

    // continuation weights k=4..7, pinned to SGPRs
    float whi[8][4];
#pragma unroll
    for (int j = 0; j < 8; ++j)
#pragma unroll
        for (int k = 0; k < 4; ++k)
            whi[j][k] = sgpr_f(W_hh[8 * j + 4 + k]);

    const float2 xv = reinterpret_cast<const float2*>(x)[i];
    float cur[8];
#pragma unroll
    for (int j = 0; j < 8; ++j) {
        float d = __fmaf_rn(xv.y, W_ih[2 * j + 1], __fmul_rn(xv.x, W_ih[2 * j]));
        cur[j] = __fadd_rn(d, b_ih[j]);
    }

    // F = 1 + #{t: c < B_t}; B_t compile-time literals. train = Tv[F]
    unsigned trn[8];
#pragma unroll
    for (int j = 0; j < 8; ++j) {
        float c = cur[j];
        unsigned cnt = 0;
#pragma unroll
        for (int t = 1; t <= 16; ++t)
            cnt += (c < kB[t]) ? 1u : 0u;
        trn[j] = Tv[cnt + 1u];
    }

    // 8x16 bit transpose -> step bytes (byte t = step t, bit j = neuron j)
    unsigned long long A = 0, A2 = 0;
#pragma unroll
    for (int j = 0; j < 8; ++j) {
        A  |= (unsigned long long)(trn[j] & 0xFFu) << (8 * j);
        A2 |= (unsigned long long)((trn[j] >> 8) & 0xFFu) << (8 * j);
    }
    A = tr8(A); A2 = tr8(A2);

    float bh[8];
#pragma unroll
    for (int j = 0; j < 8; ++j) bh[j] = b_hh[j];
    const float bho = b_ho[0];

    float m2[8] = {0.f,0.f,0.f,0.f,0.f,0.f,0.f,0.f};
    float mo = 0.f, odP = 0.f;
    unsigned tot = 0;

    float4 dvlo[2], dvhi[2];

    // prologue: issue prefix entries for steps 0,1 (low nibbles)
    {
        const unsigned q0 = (unsigned)(A) & 0xFu;
        const float4* e0 = reinterpret_cast<const float4*>(&lutA[q0 * 12]);
        dvlo[0] = e0[0]; dvhi[0] = e0[1];
        const unsigned q1 = (unsigned)(A >> 8) & 0xFu;
        const float4* e1 = reinterpret_cast<const float4*>(&lutA[q1 * 12]);
        dvlo[1] = e1[0]; dvhi[1] = e1[1];
    }

    // fully unrolled 16-step pipeline, distance-2 prefix prefetch.
#pragma unroll
    for (int t = 0; t < 16; ++t) {
        // byte for step t (static compile-time extract; A/A2 read-only)
        const unsigned bt = (t < 8)
            ? ((unsigned)(A  >> (8 * t)) & 0xFFu)
            : ((unsigned)(A2 >> (8 * (t - 8))) & 0xFFu);

        // high-nibble bits as exact {0.0f,1.0f}
        float bf[4];
#pragma unroll
        for (int k = 0; k < 4; ++k) bf[k] = (float)((bt >> (4 + k)) & 1u);

        // complete the dv chains: prefix (LDS, prefetched) + k=4..7 fma
        float dvf[8];
        dvf[0] = dvlo[t & 1].x; dvf[1] = dvlo[t & 1].y;
        dvf[2] = dvlo[t & 1].z; dvf[3] = dvlo[t & 1].w;
        dvf[4] = dvhi[t & 1].x; dvf[5] = dvhi[t & 1].y;
        dvf[6] = dvhi[t & 1].z; dvf[7] = dvhi[t & 1].w;
#pragma unroll
        for (int j = 0; j < 8; ++j) {
            float acc = dvf[j];
#pragma unroll
            for (int k = 0; k < 4; ++k)
                acc = __fmaf_rn(bf[k], whi[j][k], acc);
            dvf[j] = acc;
        }

        // L2 membrane update (descending-j pack, bitwise == ascending)
        unsigned mk2 = 0;
#pragma unroll
        for (int j = 7; j >= 0; --j) {
            float m = __fadd_rn(__fadd_rn(__fmul_rn(0.8f, m2[j]), dvf[j]), bh[j]);
            bool s = (m >= 0.5f);
            mk2 = 2u * mk2 + (s ? 1u : 0u);
            m2[j] = s ? 0.f : m;
        }

        // issue prefix for step t+2 (2x ds_read_b128, conflict-free)
        if (t + 2 < 16) {
            const int tn = t + 2;
            const unsigned bN = (tn < 8)
                ? ((unsigned)(A  >> (8 * tn)) & 0xFFu)
                : ((unsigned)(A2 >> (8 * (tn - 8))) & 0xFFu);
            const float4* en = reinterpret_cast<const float4*>(&lutA[(bN & 0xFu) * 12]);
            dvlo[t & 1] = en[0];
            dvhi[t & 1] = en[1];
        }

        // mo-update for step t-1 (consumes od_{t-1})
        if (t > 0) {
            float m = __fadd_rn(__fadd_rn(__fmul_rn(0.8f, mo), odP), bho);
            bool s = (m >= 0.5f);
            tot += s ? 1u : 0u;
            mo = s ? 0.f : m;
        }

        // issue luto_t (consumed in body t+1)
        odP = luto[mk2];
    }
    {   // epilogue: output update for step 15
        float m = __fadd_rn(__fadd_rn(__fmul_rn(0.8f, mo), odP), bho);
        tot += (m >= 0.5f) ? 1u : 0u;
    }

    out[i] = __fmul_rn((float)tot, 0.0625f);
}

extern "C" void kernel_launch(void* const* d_in, const int* in_sizes, int n_in,
                              void* d_out, int out_size, void* d_ws, size_t ws_size,
                              hipStream_t stream) {
    const float* x    = (const float*)d_in[0];
    const float* W_ih = (const float*)d_in[1];
    const float* b_ih = (const float*)d_in[2];
    const float* W_hh = (const float*)d_in[3];
    const float* b_hh = (const float*)d_in[4];
    const float* W_ho = (const float*)d_in[5];
    const float* b_ho = (const float*)d_in[6];
    float* out = (float*)d_out;

    const int n = out_size;  // 524288
    const int block = 256;
    const int grid = (n + block - 1) / block;  // 2048
    snn_kernel<<<grid, block, 0, stream>>>(x, W_ih, b_ih, W_hh, b_hh,
                                           W_ho, b_ho, out, n);
}

// Round 8
// 41.842 us; speedup vs baseline: 4.4418x; 4.4418x over previous
//
#include <hip/hip_runtime.h>

// SNN 2->8->8->1, 16 steps, leak=0.8, thr=0.5.
// R19 = R18 (4/4 LUT split) minus the scratch trigger.
//
// R18 counters: the split WORKED (SQ_LDS_BANK_CONFLICT 3.53e7 -> 4.9e5,
// 70x) but FETCH 2.2MB->214MB / WRITE 2MB->383MB = scratch-spill storm:
// readfirstlane-through-bitcast stored into local array whi[8][4]
// defeated SROA -> array in scratch -> 16x32 fills/thread (rule #20 in
// disguise). Same mechanism retro-explains R12 (whi[4][8]) and R14
// (wh[8][8]) regressions — hoisted weight AGGREGATES, not VALU cost.
// Fix: no local weight array at all. Continuation k=4..7 reads
// W_hh[8*j+4+k] DIRECTLY (literal offsets, uniform restrict pointer ->
// s_load once, SGPR-resident, v_fmac v,s,v legal) — the identical
// pattern the LUT build uses, which has never spilled.
// Predicted: FETCH ~2.2MB, WRITE ~2MB, conflicts ~5e5, VGPR ~32-48,
// dur 25.2 -> ~19-21us. If FETCH clean but dur>=24: next levers are
// preamble (P=8.7us: trn binary search) and luto->VALU.
//
// Bit-exactness invariants (absmax 0.0 R1-R18, preserved):
//  - contract(off): a*b + c stays mul+add everywhere
//  - dv_j = fma chain ascending k=0..7: lutA prefix (k=0..3) then
//    runtime fma continuation (k=4..7) is the IDENTICAL per-op sequence
//    (R18 passed absmax 0.0 with this exact split)
//  - direct W_hh loads return the same bits readfirstlane did
//  - m2 updates independent across j -> descending-j order bitwise same
//  - reset (m>=0.5 ? 0 : m) == m*(1-s) bitwise
//  - L1 exactly periodic; F = 1 + #{t: c < B_t}, B_t constexpr bit-search
//  - unified LSB convention: neuron k = bit k everywhere

// ---- compile-time breakpoint search (bit-exact f32, IEEE RN per op) ----
constexpr bool spikes_by(float c, int p) {
    float m = 0.f;
    for (int t = 0; t < p; ++t) {
        float a = 0.8f * m;
        m = a + c;
        if (m >= 0.5f) return true;
    }
    return false;
}
constexpr unsigned find_B(int p) {
    unsigned lo = 0x3D4CCCCDu;  // 0.05f: never spikes
    unsigned hi = 0x3F19999Au;  // 0.6f : spikes at step 1
    while (hi - lo > 1u) {
        unsigned mid = lo + (hi - lo) / 2u;
        if (spikes_by(__builtin_bit_cast(float, mid), p)) hi = mid;
        else lo = mid;
    }
    return hi;
}
constexpr float kB[17] = {
    0.f,
    __builtin_bit_cast(float, find_B(1)),  __builtin_bit_cast(float, find_B(2)),
    __builtin_bit_cast(float, find_B(3)),  __builtin_bit_cast(float, find_B(4)),
    __builtin_bit_cast(float, find_B(5)),  __builtin_bit_cast(float, find_B(6)),
    __builtin_bit_cast(float, find_B(7)),  __builtin_bit_cast(float, find_B(8)),
    __builtin_bit_cast(float, find_B(9)),  __builtin_bit_cast(float, find_B(10)),
    __builtin_bit_cast(float, find_B(11)), __builtin_bit_cast(float, find_B(12)),
    __builtin_bit_cast(float, find_B(13)), __builtin_bit_cast(float, find_B(14)),
    __builtin_bit_cast(float, find_B(15)), __builtin_bit_cast(float, find_B(16))
};
constexpr unsigned mk_train(int F) {
    unsigned tr = 0;
    if (F <= 16) for (int t = F; t <= 16; t += F) tr |= 1u << (t - 1);
    return tr;
}
constexpr unsigned kTv[18] = {
    0, mk_train(1), mk_train(2),  mk_train(3),  mk_train(4),  mk_train(5),
    mk_train(6),  mk_train(7),  mk_train(8),  mk_train(9),  mk_train(10),
    mk_train(11), mk_train(12), mk_train(13), mk_train(14), mk_train(15),
    mk_train(16), mk_train(17)
};

__device__ __forceinline__ unsigned long long tr8(unsigned long long x) {
    unsigned long long t;
    t = (x ^ (x >> 7))  & 0x00AA00AA00AA00AAull; x = x ^ t ^ (t << 7);
    t = (x ^ (x >> 14)) & 0x0000CCCC0000CCCCull; x = x ^ t ^ (t << 14);
    t = (x ^ (x >> 28)) & 0x00000000F0F0F0F0ull; x = x ^ t ^ (t << 28);
    return x;
}

__global__ __launch_bounds__(256, 8) void snn_kernel(
    const float* __restrict__ x,
    const float* __restrict__ W_ih, const float* __restrict__ b_ih,
    const float* __restrict__ W_hh, const float* __restrict__ b_hh,
    const float* __restrict__ W_ho, const float* __restrict__ b_ho,
    float* __restrict__ out, int n)
{
#pragma clang fp contract(off)
    // 16-entry prefix LUT, stride 12 floats (48B): 16B-aligned, 4-word
    // windows at 12q mod 32 -> 8 positions x 2 entries -> <=2-way = free.
    __shared__ __align__(16) float lutA[16 * 12];    // 768 B
    __shared__ float luto[256];                      // 1 KB
    __shared__ unsigned Tv[18];

    const int p = threadIdx.x;

    {   // builds: exact fma chains, neuron k at bit k (LSB)
        float bits[8];
#pragma unroll
        for (int k = 0; k < 8; ++k) bits[k] = (float)((p >> k) & 1);
        if (p < 16) {  // lutA entry p: chain PREFIX k=0..3 (bits of p)
            float e[8];
#pragma unroll
            for (int j = 0; j < 8; ++j) {
                float acc = 0.f;
#pragma unroll
                for (int k = 0; k < 4; ++k)
                    acc = __fmaf_rn(bits[k], W_hh[8 * j + k], acc);
                e[j] = acc;
            }
            float4* dst = reinterpret_cast<float4*>(&lutA[p * 12]);
            dst[0] = make_float4(e[0], e[1], e[2], e[3]);
            dst[1] = make_float4(e[4], e[5], e[6], e[7]);
        }
        float acc = 0.f;   // luto: full 8-bit chain (unchanged)
#pragma unroll
        for (int k = 0; k < 8; ++k)
            acc = __fmaf_rn(bits[k], W_ho[k], acc);
        luto[p] = acc;
    }
    if (p < 18) Tv[p] = kTv[p];
    __syncthreads();

    const int i = blockIdx.x * 256 + p;
    if (i >= n) return;

    const float2 xv = reinterpret_cast<const float2*>(x)[i];
    float cur[8];
#pragma unroll
    for (int j = 0; j < 8; ++j) {
        float d = __fmaf_rn(xv.y, W_ih[2 * j + 1], __fmul_rn(xv.x, W_ih[2 * j]));
        cur[j] = __fadd_rn(d, b_ih[j]);
    }

    // F = 1 + #{t: c < B_t}; B_t compile-time literals. train = Tv[F]
    unsigned trn[8];
#pragma unroll
    for (int j = 0; j < 8; ++j) {
        float c = cur[j];
        unsigned cnt = 0;
#pragma unroll
        for (int t = 1; t <= 16; ++t)
            cnt += (c < kB[t]) ? 1u : 0u;
        trn[j] = Tv[cnt + 1u];
    }

    // 8x16 bit transpose -> step bytes (byte t = step t, bit j = neuron j)
    unsigned long long A = 0, A2 = 0;
#pragma unroll
    for (int j = 0; j < 8; ++j) {
        A  |= (unsigned long long)(trn[j] & 0xFFu) << (8 * j);
        A2 |= (unsigned long long)((trn[j] >> 8) & 0xFFu) << (8 * j);
    }
    A = tr8(A); A2 = tr8(A2);

    float bh[8];
#pragma unroll
    for (int j = 0; j < 8; ++j) bh[j] = b_hh[j];
    const float bho = b_ho[0];

    float m2[8] = {0.f,0.f,0.f,0.f,0.f,0.f,0.f,0.f};
    float mo = 0.f, odP = 0.f;
    unsigned tot = 0;

    float4 dvlo[2], dvhi[2];

    // prologue: issue prefix entries for steps 0,1 (low nibbles)
    {
        const unsigned q0 = (unsigned)(A) & 0xFu;
        const float4* e0 = reinterpret_cast<const float4*>(&lutA[q0 * 12]);
        dvlo[0] = e0[0]; dvhi[0] = e0[1];
        const unsigned q1 = (unsigned)(A >> 8) & 0xFu;
        const float4* e1 = reinterpret_cast<const float4*>(&lutA[q1 * 12]);
        dvlo[1] = e1[0]; dvhi[1] = e1[1];
    }

    // fully unrolled 16-step pipeline, distance-2 prefix prefetch.
#pragma unroll
    for (int t = 0; t < 16; ++t) {
        // byte for step t (static compile-time extract; A/A2 read-only)
        const unsigned bt = (t < 8)
            ? ((unsigned)(A  >> (8 * t)) & 0xFFu)
            : ((unsigned)(A2 >> (8 * (t - 8))) & 0xFFu);

        // high-nibble bits as exact {0.0f,1.0f}
        float bf[4];
#pragma unroll
        for (int k = 0; k < 4; ++k) bf[k] = (float)((bt >> (4 + k)) & 1u);

        // complete the dv chains: prefix (LDS, prefetched) + k=4..7 fma.
        // W_hh read DIRECTLY (uniform + literal offset -> s_load/SGPR;
        // no local aggregate -> no scratch).
        float dvf[8];
        dvf[0] = dvlo[t & 1].x; dvf[1] = dvlo[t & 1].y;
        dvf[2] = dvlo[t & 1].z; dvf[3] = dvlo[t & 1].w;
        dvf[4] = dvhi[t & 1].x; dvf[5] = dvhi[t & 1].y;
        dvf[6] = dvhi[t & 1].z; dvf[7] = dvhi[t & 1].w;
#pragma unroll
        for (int j = 0; j < 8; ++j) {
            float acc = dvf[j];
#pragma unroll
            for (int k = 0; k < 4; ++k)
                acc = __fmaf_rn(bf[k], W_hh[8 * j + 4 + k], acc);
            dvf[j] = acc;
        }

        // L2 membrane update (descending-j pack, bitwise == ascending)
        unsigned mk2 = 0;
#pragma unroll
        for (int j = 7; j >= 0; --j) {
            float m = __fadd_rn(__fadd_rn(__fmul_rn(0.8f, m2[j]), dvf[j]), bh[j]);
            bool s = (m >= 0.5f);
            mk2 = 2u * mk2 + (s ? 1u : 0u);
            m2[j] = s ? 0.f : m;
        }

        // issue prefix for step t+2 (2x ds_read_b128, conflict-free)
        if (t + 2 < 16) {
            const int tn = t + 2;
            const unsigned bN = (tn < 8)
                ? ((unsigned)(A  >> (8 * tn)) & 0xFFu)
                : ((unsigned)(A2 >> (8 * (tn - 8))) & 0xFFu);
            const float4* en = reinterpret_cast<const float4*>(&lutA[(bN & 0xFu) * 12]);
            dvlo[t & 1] = en[0];
            dvhi[t & 1] = en[1];
        }

        // mo-update for step t-1 (consumes od_{t-1})
        if (t > 0) {
            float m = __fadd_rn(__fadd_rn(__fmul_rn(0.8f, mo), odP), bho);
            bool s = (m >= 0.5f);
            tot += s ? 1u : 0u;
            mo = s ? 0.f : m;
        }

        // issue luto_t (consumed in body t+1)
        odP = luto[mk2];
    }
    {   // epilogue: output update for step 15
        float m = __fadd_rn(__fadd_rn(__fmul_rn(0.8f, mo), odP), bho);
        tot += (m >= 0.5f) ? 1u : 0u;
    }

    out[i] = __fmul_rn((float)tot, 0.0625f);
}

extern "C" void kernel_launch(void* const* d_in, const int* in_sizes, int n_in,
                              void* d_out, int out_size, void* d_ws, size_t ws_size,
                              hipStream_t stream) {
    const float* x    = (const float*)d_in[0];
    const float* W_ih = (const float*)d_in[1];
    const float* b_ih = (const float*)d_in[2];
    const float* W_hh = (const float*)d_in[3];
    const float* b_hh = (const float*)d_in[4];
    const float* W_ho = (const float*)d_in[5];
    const float* b_ho = (const float*)d_in[6];
    float* out = (float*)d_out;

    const int n = out_size;  // 524288
    const int block = 256;
    const int grid = (n + block - 1) / block;  // 2048
    snn_kernel<<<grid, block, 0, stream>>>(x, W_ih, b_ih, W_hh, b_hh,
                                           W_ho, b_ho, out, n);
}